// Round 14
// baseline (599.564 us; speedup 1.0000x reference)
//
#include <hip/hip_runtime.h>

typedef __attribute__((ext_vector_type(4))) float f32x4;
typedef __attribute__((ext_vector_type(8))) _Float16 f16x8;

#define NSRC 8192
#define MANC 4096
#define QDIM 4096
#define VDIM 512
#define DM   1024
#define FFD  2048

__device__ __forceinline__ ushort f2h(float f){ _Float16 h=(_Float16)f; return __builtin_bit_cast(ushort,h); }
__device__ __forceinline__ float h2f(ushort u){ _Float16 h=__builtin_bit_cast(_Float16,u); return (float)h; }
__device__ __forceinline__ uint pk2(float a,float b){ return (uint)f2h(a) | ((uint)f2h(b)<<16); }

__device__ __forceinline__ void gload16(const ushort* g, ushort* l){
  __builtin_amdgcn_global_load_lds(
    (const __attribute__((address_space(1))) unsigned int*)g,
    (__attribute__((address_space(3))) unsigned int*)l, 16, 0, 0);
}

// ---------- f32 -> f16 convert: src (16384 blocks) + a1 (8192 blocks), one streaming dispatch ----------
__global__ __launch_bounds__(256) void k_conv(const float* __restrict__ src, ushort* __restrict__ src_h,
                                              const float* __restrict__ a1, ushort* __restrict__ a1_h){
  int b = blockIdx.x;
  const float* in; ushort* out; long i;
  if (b < 16384){ in = src; out = src_h; i = ((long)b*256 + threadIdx.x)*8; }
  else          { in = a1;  out = a1_h;  i = ((long)(b-16384)*256 + threadIdx.x)*8; }
  float4 a = *(const float4*)(in+i);
  float4 c = *(const float4*)(in+i+4);
  uint4 o; o.x=pk2(a.x,a.y); o.y=pk2(a.z,a.w); o.z=pk2(c.x,c.y); o.w=pk2(c.z,c.w);
  *(uint4*)(out+i) = o;
}

// ---------- merged weight transposes + stat-buffer zeroing ----------
__device__ __forceinline__ void tr32(const float* __restrict__ W, ushort* __restrict__ WT,
                                     int K, int N, int bx, int by, int tid){
  __shared__ float tile[32][33];
  int n0 = bx*32, k0 = by*32;
  int tx = tid & 31, ty = tid >> 5;
  #pragma unroll
  for (int i=0;i<4;++i) tile[ty+i*8][tx] = W[(long)(k0+ty+i*8)*N + n0+tx];
  __syncthreads();
  #pragma unroll
  for (int i=0;i<4;++i){ int nn=ty+i*8; WT[(long)(n0+nn)*K + k0+tx] = f2h(tile[tx][nn]); }
}
__global__ __launch_bounds__(256) void k_prep(const float* __restrict__ Wq, const float* __restrict__ Wv,
    const float* __restrict__ W1, const float* __restrict__ W2, const float* __restrict__ Wd,
    ushort* __restrict__ WqT, ushort* __restrict__ WvT, ushort* __restrict__ W1T,
    ushort* __restrict__ W2T, ushort* __restrict__ WdT, float* __restrict__ zbase){
  int b = blockIdx.x, t = threadIdx.x;
  if (b < 4096)                 tr32(Wq, WqT, QDIM, DM,  b % 32,        b / 32,        t);
  else if (b < 4608)            tr32(Wv, WvT, VDIM, DM,  (b-4096)%32,   (b-4096)/32,   t);
  else if (b < 6656)            tr32(W1, W1T, DM,  FFD,  (b-4608)%64,   (b-4608)/64,   t);
  else if (b < 8704)            tr32(W2, W2T, FFD, DM,   (b-6656)%32,   (b-6656)/32,   t);
  else if (b < 9216)            tr32(Wd, WdT, DM,  VDIM, (b-8704)%16,   (b-8704)/16,   t);
  else { for (int i = t; i < 5120; i += 256) zbase[i] = 0.f; }   // ps1,pq1,ps2,pq2,psd,pqd
}

// ============ 16-wave TLP GEMM: 1024 thr, 256xBN tile, double-buffered ============
// __launch_bounds__(1024,4): 1 block/CU -> 128 VGPR cap, no spill (round 9 verified).
// STATS (EPI 3/5): finalize output in acc-space, per-col sum/sumsq, shfl-reduce
// across kg, one atomicAdd per column per block.
// EPI: 0 f16+bias | 2 f16 *alpha*extra(f32) | 3 f32 (*alpha, +stats) | 4 f16 tanh(+bias) | 5 f32 (+bias+extra(f16), +stats)
template<int EPI, int BIG>
__global__ __launch_bounds__(1024, 4) void k_gemmT(const ushort* __restrict__ A, const ushort* __restrict__ Bt,
    int M, int N, int K, const float* __restrict__ bias, const void* __restrict__ extra,
    float alpha, float* __restrict__ Cf, ushort* __restrict__ Ch,
    float* __restrict__ psum, float* __restrict__ pqsum, int gxm1, int lg2gx)
{
  extern __shared__ ushort lds[];
  constexpr int BN   = BIG ? 256 : 128;
  constexpr int NI   = BIG ? 4 : 2;
  constexpr int WN   = NI * 16;
  constexpr int BSH  = BIG ? 16384 : 8192;
  constexpr int HALF = 16384 + BSH;
  constexpr int BJ   = BIG ? 2 : 1;
  const int tid = threadIdx.x, lane = tid & 63, w = tid >> 6;
  const int wm = (w >> 2) * 64, wn = (w & 3) * WN;
  int id = blockIdx.x;
  int nid = (id & 7) * ((int)gridDim.x >> 3) + (id >> 3);
  const int m0 = (nid >> lg2gx) * 256, n0 = (nid & gxm1) * BN;
  const int lr = lane & 15, kg = lane >> 4;
  f32x4 acc[4][NI] = {};
  const int nkt = K >> 6;
  const ushort* Ap = A + (long)m0 * K;
  const ushort* Bp = Bt + (long)n0 * K;
  int ra[2], ca[2];
  #pragma unroll
  for (int j = 0; j < 2; ++j){ int c = j*1024 + tid; ra[j] = c >> 3; ca[j] = (c & 7) ^ (ra[j] & 7); }
  auto stage = [&](int t, int buf){
    long ko = (long)t * 64;
    ushort* As = lds + buf*HALF;
    ushort* Bs = As + 16384;
    #pragma unroll
    for (int j = 0; j < 2; ++j)  gload16(Ap + (long)ra[j]*K + ko + ca[j]*8, As + (j*1024 + tid)*8);
    #pragma unroll
    for (int j = 0; j < BJ; ++j) gload16(Bp + (long)ra[j]*K + ko + ca[j]*8, Bs + (j*1024 + tid)*8);
  };
  stage(0, 0);
  __syncthreads();
  int cur = 0;
  for (int t = 0; t < nkt; ++t){
    if (t + 1 < nkt) stage(t + 1, cur ^ 1);   // issue first: full-tile latency lead
    const ushort* Ab = lds + cur*HALF;
    const ushort* Bb = Ab + 16384;
    f16x8 af[4], bf[NI];
    #pragma unroll
    for (int mi=0;mi<4;++mi){ int r = wm + mi*16 + lr; af[mi] = *(const f16x8*)&Ab[r*64 + ((kg ^ (r&7))*8)]; }
    #pragma unroll
    for (int ni=0;ni<NI;++ni){ int r = wn + ni*16 + lr; bf[ni] = *(const f16x8*)&Bb[r*64 + ((kg ^ (r&7))*8)]; }
    __builtin_amdgcn_s_setprio(1);
    #pragma unroll
    for (int mi=0;mi<4;++mi)
      #pragma unroll
      for (int ni=0;ni<NI;++ni)
        acc[mi][ni] = __builtin_amdgcn_mfma_f32_16x16x32_f16(af[mi], bf[ni], acc[mi][ni], 0,0,0);
    __builtin_amdgcn_s_setprio(0);
    #pragma unroll
    for (int mi=0;mi<4;++mi){ int r = wm + mi*16 + lr; af[mi] = *(const f16x8*)&Ab[r*64 + (((4+kg) ^ (r&7))*8)]; }
    #pragma unroll
    for (int ni=0;ni<NI;++ni){ int r = wn + ni*16 + lr; bf[ni] = *(const f16x8*)&Bb[r*64 + (((4+kg) ^ (r&7))*8)]; }
    __builtin_amdgcn_s_setprio(1);
    #pragma unroll
    for (int mi=0;mi<4;++mi)
      #pragma unroll
      for (int ni=0;ni<NI;++ni)
        acc[mi][ni] = __builtin_amdgcn_mfma_f32_16x16x32_f16(af[mi], bf[ni], acc[mi][ni], 0,0,0);
    __builtin_amdgcn_s_setprio(0);
    __syncthreads();                          // drains vm+lgkm: buf^1 staged, buf free
    cur ^= 1;
  }
  // ---- stats + acc-space finalize for EPI 3/5 ----
  if (EPI==3 || EPI==5){
    #pragma unroll
    for (int ni=0;ni<NI;++ni){
      int col = n0 + wn + ni*16 + lr;
      float bcol = (EPI==5) ? bias[col] : 0.f;
      float s = 0.f, q = 0.f;
      #pragma unroll
      for (int mi=0;mi<4;++mi){
        #pragma unroll
        for (int r=0;r<4;++r){
          float v = acc[mi][ni][r];
          if (EPI==3) v *= alpha;
          else {
            int row = m0 + wm + mi*16 + kg*4 + r;
            v += bcol + h2f(((const ushort*)extra)[(long)row*N + col]);
          }
          acc[mi][ni][r] = v;
          s += v; q += v*v;
        }
      }
      s += __shfl_xor(s,16); s += __shfl_xor(s,32);
      q += __shfl_xor(q,16); q += __shfl_xor(q,32);
      if (kg==0){ atomicAdd(&psum[col], s); atomicAdd(&pqsum[col], q); }
    }
  }
  // ---- epilogue: per-wave 64xWN transpose via LDS -> coalesced stores ----
  __syncthreads();
  float* Lw = ((float*)lds) + w * 16 * WN;
  #pragma unroll
  for (int mi = 0; mi < 4; ++mi){
    #pragma unroll
    for (int ni = 0; ni < NI; ++ni)
      #pragma unroll
      for (int r = 0; r < 4; ++r)
        Lw[(kg*4+r)*WN + ni*16 + lr] = acc[mi][ni][r];
    __syncthreads();
    #pragma unroll
    for (int tt = 0; tt < WN/16; ++tt){
      int fi = tt*64 + lane;
      int row16 = fi / (WN/4), c4 = fi % (WN/4);
      float4 v4 = *(float4*)&Lw[row16*WN + c4*4];
      int row = m0 + wm + mi*16 + row16;
      int col = n0 + wn + c4*4;
      if (EPI==0){
        float4 b4 = *(const float4*)&bias[col];
        ushort4 o; o.x=f2h(v4.x+b4.x); o.y=f2h(v4.y+b4.y); o.z=f2h(v4.z+b4.z); o.w=f2h(v4.w+b4.w);
        *(ushort4*)&Ch[(long)row*N + col] = o;
      } else if (EPI==2){
        float4 e4 = *(const float4*)((const float*)extra + (long)row*N + col);
        ushort4 o; o.x=f2h(v4.x*alpha*e4.x); o.y=f2h(v4.y*alpha*e4.y);
        o.z=f2h(v4.z*alpha*e4.z); o.w=f2h(v4.w*alpha*e4.w);
        *(ushort4*)&Ch[(long)row*N + col] = o;
      } else if (EPI==3 || EPI==5){
        *(float4*)&Cf[(long)row*N + col] = v4;   // finalized in acc-space
      } else if (EPI==4){
        float4 b4 = *(const float4*)&bias[col];
        ushort4 o; o.x=f2h(tanhf(v4.x+b4.x)); o.y=f2h(tanhf(v4.y+b4.y));
        o.z=f2h(tanhf(v4.z+b4.z)); o.w=f2h(tanhf(v4.w+b4.w));
        *(ushort4*)&Ch[(long)row*N + col] = o;
      }
    }
    __syncthreads();
  }
}

// ---------- legacy 128x128 GEMM (K, V^T, decoder) ----------
// EPI: 0 f16 out +bias | 1 f16 out transposed +bias | 6 f32 out +bias (+stats)
template<int EPI, bool A32>
__global__ __launch_bounds__(256) void k_gemm(const void* __restrict__ Av, const ushort* __restrict__ Bt,
    int M, int N, int K, const float* __restrict__ bias,
    float alpha, float* __restrict__ Cf, ushort* __restrict__ Ch,
    float* __restrict__ psum, float* __restrict__ pqsum, int gxm1, int lg2gx)
{
  __shared__ ushort As[128*64];
  __shared__ ushort Bs[128*64];
  const int tid = threadIdx.x, lane = tid & 63, w = tid>>6;
  const int wm = (w>>1)*64, wn = (w&1)*64;
  int id = blockIdx.x;
  int nid = (id & 7)*((int)gridDim.x >> 3) + (id >> 3);
  const int m0 = (nid >> lg2gx)*128, n0 = (nid & gxm1)*128;
  const int lr = lane & 15, kg = lane >> 4;
  f32x4 acc[4][4] = {};
  const int nkt = K >> 6;
  const ushort* Ah = (const ushort*)Av + (A32 ? 0 : (long)m0*K);
  const float*  Af = (const float*)Av  + (A32 ? (long)m0*K : 0);
  const ushort* Bp = Bt + (long)n0*K;
  int rowj[4], colj[4];
  #pragma unroll
  for (int j=0;j<4;++j){
    int c = w*256 + j*64 + lane;
    rowj[j] = c>>3; colj[j] = (c&7) ^ (rowj[j]&7);
  }
  float4 pa[4][2];
  if (A32){
    #pragma unroll
    for (int j=0;j<4;++j){
      const float* s = Af + (long)rowj[j]*K + colj[j]*8;
      pa[j][0] = *(const float4*)s; pa[j][1] = *(const float4*)(s+4);
    }
  }
  for (int kt=0; kt<nkt; ++kt){
    __syncthreads();
    long ko = (long)kt*64;
    if (A32){
      #pragma unroll
      for (int j=0;j<4;++j){
        uint4 o; o.x=pk2(pa[j][0].x,pa[j][0].y); o.y=pk2(pa[j][0].z,pa[j][0].w);
        o.z=pk2(pa[j][1].x,pa[j][1].y); o.w=pk2(pa[j][1].z,pa[j][1].w);
        *(uint4*)&As[(w*256 + j*64 + lane)*8] = o;
      }
    } else {
      #pragma unroll
      for (int j=0;j<4;++j)
        gload16(Ah + (long)rowj[j]*K + ko + colj[j]*8, As + (w*4+j)*512);
    }
    #pragma unroll
    for (int j=0;j<4;++j)
      gload16(Bp + (long)rowj[j]*K + ko + colj[j]*8, Bs + (w*4+j)*512);
    __syncthreads();
    if (A32 && kt+1 < nkt){
      long ko2 = ko + 64;
      #pragma unroll
      for (int j=0;j<4;++j){
        const float* s = Af + (long)rowj[j]*K + ko2 + colj[j]*8;
        pa[j][0] = *(const float4*)s; pa[j][1] = *(const float4*)(s+4);
      }
    }
    #pragma unroll
    for (int ks=0; ks<2; ++ks){
      f16x8 af[4], bfr[4];
      #pragma unroll
      for (int mi=0;mi<4;++mi){
        int r = wm + mi*16 + lr, c = ks*4 + kg;
        af[mi] = *(const f16x8*)&As[r*64 + ((c ^ (r&7))*8)];
      }
      #pragma unroll
      for (int ni=0;ni<4;++ni){
        int r = wn + ni*16 + lr, c = ks*4 + kg;
        bfr[ni] = *(const f16x8*)&Bs[r*64 + ((c ^ (r&7))*8)];
      }
      #pragma unroll
      for (int mi=0;mi<4;++mi)
        #pragma unroll
        for (int ni=0;ni<4;++ni)
          acc[mi][ni] = __builtin_amdgcn_mfma_f32_16x16x32_f16(af[mi], bfr[ni], acc[mi][ni], 0,0,0);
    }
  }
  if (EPI==6){   // bias + stats in acc-space
    #pragma unroll
    for (int ni=0;ni<4;++ni){
      int col = n0 + wn + ni*16 + lr;
      float bcol = bias[col];
      float s = 0.f, q = 0.f;
      #pragma unroll
      for (int mi=0;mi<4;++mi)
        #pragma unroll
        for (int r=0;r<4;++r){
          float v = acc[mi][ni][r] + bcol;
          acc[mi][ni][r] = v;
          s += v; q += v*v;
        }
      s += __shfl_xor(s,16); s += __shfl_xor(s,32);
      q += __shfl_xor(q,16); q += __shfl_xor(q,32);
      if (kg==0){ atomicAdd(&psum[col], s); atomicAdd(&pqsum[col], q); }
    }
  }
  __syncthreads();
  float* Lw = ((float*)As) + w*1024;
  #pragma unroll
  for (int mi=0;mi<4;++mi){
    #pragma unroll
    for (int ni=0;ni<4;++ni)
      #pragma unroll
      for (int r=0;r<4;++r)
        Lw[(kg*4+r)*64 + ni*16 + lr] = acc[mi][ni][r];
    __syncthreads();
    #pragma unroll
    for (int t=0;t<4;++t){
      int fi = t*64 + lane;
      int row16 = fi >> 4, c4 = fi & 15;
      float4 v4 = *(float4*)&Lw[row16*64 + c4*4];
      int row = m0 + wm + mi*16 + row16;
      int col = n0 + wn + c4*4;
      if (EPI==0){
        float4 b4 = *(const float4*)&bias[col];
        ushort4 o; o.x=f2h(v4.x+b4.x); o.y=f2h(v4.y+b4.y); o.z=f2h(v4.z+b4.z); o.w=f2h(v4.w+b4.w);
        *(ushort4*)&Ch[(long)row*N + col] = o;
      } else if (EPI==1){
        float4 b4 = *(const float4*)&bias[col];
        Ch[(long)(col+0)*M + row] = f2h(v4.x+b4.x);
        Ch[(long)(col+1)*M + row] = f2h(v4.y+b4.y);
        Ch[(long)(col+2)*M + row] = f2h(v4.z+b4.z);
        Ch[(long)(col+3)*M + row] = f2h(v4.w+b4.w);
      } else {
        *(float4*)&Cf[(long)row*N + col] = v4;   // EPI6: bias already applied
      }
    }
    __syncthreads();
  }
}

// ---------- row softmax over 4096 f16 cols, writes prob*512 as f16 ----------
__global__ __launch_bounds__(256) void k_softmax(const ushort* __restrict__ S, ushort* __restrict__ P){
  const long base = (long)blockIdx.x * 4096;
  const int t = threadIdx.x;
  uint u[8];
  *(uint4*)&u[0] = *(const uint4*)(S + base + t*16);
  *(uint4*)&u[4] = *(const uint4*)(S + base + t*16 + 8);
  float v[16];
  #pragma unroll
  for (int i=0;i<8;++i){ v[2*i]=h2f((ushort)(u[i]&0xffff)); v[2*i+1]=h2f((ushort)(u[i]>>16)); }
  float mx = -3.4e38f;
  #pragma unroll
  for (int i=0;i<16;++i) mx = fmaxf(mx, v[i]);
  #pragma unroll
  for (int off=1; off<64; off<<=1) mx = fmaxf(mx, __shfl_xor(mx, off));
  __shared__ float red[8];
  int wv = t>>6;
  if ((t&63)==0) red[wv]=mx;
  __syncthreads();
  mx = fmaxf(fmaxf(red[0],red[1]), fmaxf(red[2],red[3]));
  float e[16]; float sum=0.f;
  #pragma unroll
  for (int i=0;i<16;++i){ e[i]=__expf(v[i]-mx); sum+=e[i]; }
  #pragma unroll
  for (int off=1; off<64; off<<=1) sum += __shfl_xor(sum, off);
  if ((t&63)==0) red[4+wv]=sum;
  __syncthreads();
  sum = red[4]+red[5]+red[6]+red[7];
  float s = 512.f/sum;
  uint o[8];
  #pragma unroll
  for (int i=0;i<8;++i) o[i]=pk2(e[2*i]*s, e[2*i+1]*s);
  *(uint4*)(P + base + t*16)     = *(uint4*)&o[0];
  *(uint4*)(P + base + t*16 + 8) = *(uint4*)&o[4];
}

// ---------- batchnorm: finalize / apply ----------
__global__ __launch_bounds__(256) void k_bn_final(const float* __restrict__ ps, const float* __restrict__ pq,
    const float* __restrict__ gamma, const float* __restrict__ beta,
    float* __restrict__ scale, float* __restrict__ shift, int F, float invN, int nch){
  int c = blockIdx.x*256 + threadIdx.x;
  if (c>=F) return;
  float s=0.f,q=0.f;
  for (int i=0;i<nch;++i){ s+=ps[i*F+c]; q+=pq[i*F+c]; }
  float mu = s*invN, var = q*invN - mu*mu;
  float sc = gamma[c]*rsqrtf(var+1e-5f);
  scale[c]=sc; shift[c]=beta[c]-mu*sc;
}
__global__ __launch_bounds__(256) void k_bn_apply(const float* __restrict__ X, const float* __restrict__ scale, const float* __restrict__ shift,
    ushort* __restrict__ Xh, int F, long n){
  long i = ((long)blockIdx.x*256 + threadIdx.x)*4;
  if (i>=n) return;
  int c = (int)(i & (long)(F-1));
  float4 x = *(const float4*)(X+i);
  ushort4 o; o.x=f2h(x.x*scale[c]+shift[c]); o.y=f2h(x.y*scale[c+1]+shift[c+1]);
  o.z=f2h(x.z*scale[c+2]+shift[c+2]); o.w=f2h(x.w*scale[c+3]+shift[c+3]);
  *(ushort4*)(Xh+i)=o;
}
__global__ __launch_bounds__(256) void k_bn_tanh(const float* __restrict__ X, const float* __restrict__ scale, const float* __restrict__ shift,
    float* __restrict__ O, int F, long n){
  long i = ((long)blockIdx.x*256 + threadIdx.x)*4;
  if (i>=n) return;
  int c = (int)(i & (long)(F-1));
  float4 x = *(const float4*)(X+i);
  float4 y; y.x=tanhf(x.x*scale[c]+shift[c]); y.y=tanhf(x.y*scale[c+1]+shift[c+1]);
  y.z=tanhf(x.z*scale[c+2]+shift[c+2]); y.w=tanhf(x.w*scale[c+3]+shift[c+3]);
  *(float4*)(O+i)=y;
}

extern "C" void kernel_launch(void* const* d_in, const int* in_sizes, int n_in,
                              void* d_out, int out_size, void* d_ws, size_t ws_size,
                              hipStream_t stream){
  const float* src = (const float*)d_in[0];
  const float* a1  = (const float*)d_in[1];
  const float* a2  = (const float*)d_in[2];
  const float* lg  = (const float*)d_in[3];
  const float* Wq  = (const float*)d_in[4];
  const float* bq  = (const float*)d_in[5];
  const float* Wv  = (const float*)d_in[6];
  const float* bv  = (const float*)d_in[7];
  const float* W1  = (const float*)d_in[8];
  const float* b1  = (const float*)d_in[9];
  const float* W2  = (const float*)d_in[10];
  const float* b2  = (const float*)d_in[11];
  const float* g1  = (const float*)d_in[12];
  const float* be1 = (const float*)d_in[13];
  const float* g2  = (const float*)d_in[14];
  const float* be2 = (const float*)d_in[15];
  const float* Wd  = (const float*)d_in[16];
  const float* bd  = (const float*)d_in[17];
  const float* gd  = (const float*)d_in[18];
  const float* bed = (const float*)d_in[19];
  char* ws = (char*)d_ws;
  // region R0: src_h f16 [0,64M) -> scores f16 [0,64M) -> x_att f32 [0,32M)
  ushort* src_h = (ushort*)(ws + 0);
  ushort* scores= (ushort*)(ws + 0);
  float*  x_att = (float*) (ws + 0);
  // region R0b [64M,112M): a1_h f16 [64,96M) (conv->K) ; later xnb [64,80M), hbuf [80,112M)
  ushort* a1_h  = (ushort*)(ws + 67108864);
  ushort* xnb   = (ushort*)(ws + 67108864);
  ushort* hbuf  = (ushort*)(ws + 83886080);
  // region R1: prob f16 [128,192M) -> x2 f32 [128,160), x2nb [160,176), y [176,192)
  ushort* prob  = (ushort*)(ws + 134217728);
  float*  x2    = (float*) (ws + 134217728);
  ushort* x2nb  = (ushort*)(ws + 167772160);
  float*  y     = (float*) (ws + 184549376);
  // persistent (>=192MiB)
  ushort* Qh    = (ushort*)(ws + 201326592);
  ushort* Kh    = (ushort*)(ws + 218103808);
  ushort* VTh   = (ushort*)(ws + 226492416);
  ushort* WqT   = (ushort*)(ws + 234881024);
  ushort* WvT   = (ushort*)(ws + 243269632);
  ushort* W1T   = (ushort*)(ws + 244318208);
  ushort* W2T   = (ushort*)(ws + 248512512);
  ushort* WdT   = (ushort*)(ws + 252706816);
  float*  sc1   = (float*) (ws + 254017536);
  float*  sh1   = (float*) (ws + 254021632);
  float*  sc2   = (float*) (ws + 254025728);
  float*  sh2   = (float*) (ws + 254029824);
  float*  scd   = (float*) (ws + 254033920);
  float*  shd   = (float*) (ws + 254035968);
  // BN stat buffers (contiguous, zeroed by k_prep)
  float*  ps1   = (float*) (ws + 254038016);
  float*  pq1   = (float*) (ws + 254042112);
  float*  ps2   = (float*) (ws + 254046208);
  float*  pq2   = (float*) (ws + 254050304);
  float*  psd   = (float*) (ws + 254054400);
  float*  pqd   = (float*) (ws + 254056448);

  (void)hipFuncSetAttribute((const void*)k_gemmT<0,0>, hipFuncAttributeMaxDynamicSharedMemorySize, 98304);
  (void)hipFuncSetAttribute((const void*)k_gemmT<2,1>, hipFuncAttributeMaxDynamicSharedMemorySize, 131072);
  (void)hipFuncSetAttribute((const void*)k_gemmT<3,0>, hipFuncAttributeMaxDynamicSharedMemorySize, 98304);
  (void)hipFuncSetAttribute((const void*)k_gemmT<4,1>, hipFuncAttributeMaxDynamicSharedMemorySize, 131072);
  (void)hipFuncSetAttribute((const void*)k_gemmT<5,0>, hipFuncAttributeMaxDynamicSharedMemorySize, 98304);

  dim3 b256(256), b1024(1024);
  // streaming conversions (src + a1, homogeneous) and latency-bound prep (transposes + zero) kept separate
  k_conv<<<dim3(24576), b256, 0, stream>>>(src, src_h, a1, a1_h);
  k_prep<<<dim3(9217), b256, 0, stream>>>(Wq, Wv, W1, W2, Wd, WqT, WvT, W1T, W2T, WdT, ps1);
  // Q (gemmT SMALL), K (legacy gload path, f16 a1_h), V^T (legacy A32 fused)
  k_gemmT<0,0><<<dim3(256), b1024, 98304, stream>>>(src_h, WqT, NSRC, DM, QDIM, bq, nullptr, 1.f, nullptr, Qh, nullptr, nullptr, 7, 3);
  k_gemm<0,false><<<dim3(256), b256, 0, stream>>>(a1_h, WqT, MANC, DM, QDIM, bq, 1.f, nullptr, Kh, nullptr, nullptr, 7, 3);
  k_gemm<1,true><<<dim3(256), b256, 0, stream>>>(a2, WvT, MANC, DM, VDIM, bv, 1.f, nullptr, VTh, nullptr, nullptr, 7, 3);
  // scores(f16) = (Q K^T)/32 * label_graph ; softmax(f16) ; x = prob V (+BN1 stats)
  k_gemmT<2,1><<<dim3(512), b1024, 131072, stream>>>(Qh, Kh, NSRC, MANC, DM, nullptr, lg, 0.03125f, nullptr, scores, nullptr, nullptr, 15, 4);
  k_softmax<<<dim3(NSRC), b256, 0, stream>>>(scores, prob);
  k_gemmT<3,0><<<dim3(256), b1024, 98304, stream>>>(prob, VTh, NSRC, DM, MANC, nullptr, nullptr, 1.f/512.f, x_att, nullptr, ps1, pq1, 7, 3);
  // BN1
  k_bn_final<<<dim3(DM/256), b256, 0, stream>>>(ps1, pq1, g1, be1, sc1, sh1, DM, 1.f/NSRC, 1);
  k_bn_apply<<<dim3(8192), b256, 0, stream>>>(x_att, sc1, sh1, xnb, DM, (long)NSRC*DM);
  // FFN (FFN2 fuses residual + BN2 stats)
  k_gemmT<4,1><<<dim3(256), b1024, 131072, stream>>>(xnb, W1T, NSRC, FFD, DM, b1, nullptr, 1.f, nullptr, hbuf, nullptr, nullptr, 7, 3);
  k_gemmT<5,0><<<dim3(256), b1024, 98304, stream>>>(hbuf, W2T, NSRC, DM, FFD, b2, xnb, 1.f, x2, nullptr, ps2, pq2, 7, 3);
  // BN2
  k_bn_final<<<dim3(DM/256), b256, 0, stream>>>(ps2, pq2, g2, be2, sc2, sh2, DM, 1.f/NSRC, 1);
  k_bn_apply<<<dim3(8192), b256, 0, stream>>>(x2, sc2, sh2, x2nb, DM, (long)NSRC*DM);
  // decoder (+BNd stats) + BN + tanh
  k_gemm<6,false><<<dim3(256), b256, 0, stream>>>(x2nb, WdT, NSRC, VDIM, DM, bd, 1.f, y, nullptr, psd, pqd, 3, 2);
  k_bn_final<<<dim3(2), b256, 0, stream>>>(psd, pqd, gd, bed, scd, shd, VDIM, 1.f/NSRC, 1);
  k_bn_tanh<<<dim3(4096), b256, 0, stream>>>(y, scd, shd, (float*)d_out, VDIM, (long)NSRC*VDIM);
}

// Round 15
// 586.802 us; speedup vs baseline: 1.0217x; 1.0217x over previous
//
#include <hip/hip_runtime.h>

typedef __attribute__((ext_vector_type(4))) float f32x4;
typedef __attribute__((ext_vector_type(8))) _Float16 f16x8;

#define NSRC 8192
#define MANC 4096
#define QDIM 4096
#define VDIM 512
#define DM   1024
#define FFD  2048

__device__ __forceinline__ ushort f2h(float f){ _Float16 h=(_Float16)f; return __builtin_bit_cast(ushort,h); }
__device__ __forceinline__ float h2f(ushort u){ _Float16 h=__builtin_bit_cast(_Float16,u); return (float)h; }
__device__ __forceinline__ uint pk2(float a,float b){ return (uint)f2h(a) | ((uint)f2h(b)<<16); }

__device__ __forceinline__ void gload16(const ushort* g, ushort* l){
  __builtin_amdgcn_global_load_lds(
    (const __attribute__((address_space(1))) unsigned int*)g,
    (__attribute__((address_space(3))) unsigned int*)l, 16, 0, 0);
}

// ---------- f32 -> f16 convert (one tensor per dispatch; keep pre-Q timeline == round 12) ----------
__global__ __launch_bounds__(256) void k_conv(const float* __restrict__ in, ushort* __restrict__ out, long n){
  long i = ((long)blockIdx.x*256 + threadIdx.x)*8;
  if (i >= n) return;
  float4 a = *(const float4*)(in+i);
  float4 b = *(const float4*)(in+i+4);
  uint4 o; o.x=pk2(a.x,a.y); o.y=pk2(a.z,a.w); o.z=pk2(b.x,b.y); o.w=pk2(b.z,b.w);
  *(uint4*)(out+i) = o;
}

// ---------- merged weight transposes + stat-buffer zeroing ----------
__device__ __forceinline__ void tr32(const float* __restrict__ W, ushort* __restrict__ WT,
                                     int K, int N, int bx, int by, int tid){
  __shared__ float tile[32][33];
  int n0 = bx*32, k0 = by*32;
  int tx = tid & 31, ty = tid >> 5;
  #pragma unroll
  for (int i=0;i<4;++i) tile[ty+i*8][tx] = W[(long)(k0+ty+i*8)*N + n0+tx];
  __syncthreads();
  #pragma unroll
  for (int i=0;i<4;++i){ int nn=ty+i*8; WT[(long)(n0+nn)*K + k0+tx] = f2h(tile[tx][nn]); }
}
__global__ __launch_bounds__(256) void k_prep(const float* __restrict__ Wq, const float* __restrict__ Wv,
    const float* __restrict__ W1, const float* __restrict__ W2, const float* __restrict__ Wd,
    ushort* __restrict__ WqT, ushort* __restrict__ WvT, ushort* __restrict__ W1T,
    ushort* __restrict__ W2T, ushort* __restrict__ WdT, float* __restrict__ zbase){
  int b = blockIdx.x, t = threadIdx.x;
  if (b < 4096)                 tr32(Wq, WqT, QDIM, DM,  b % 32,        b / 32,        t);
  else if (b < 4608)            tr32(Wv, WvT, VDIM, DM,  (b-4096)%32,   (b-4096)/32,   t);
  else if (b < 6656)            tr32(W1, W1T, DM,  FFD,  (b-4608)%64,   (b-4608)/64,   t);
  else if (b < 8704)            tr32(W2, W2T, FFD, DM,   (b-6656)%32,   (b-6656)/32,   t);
  else if (b < 9216)            tr32(Wd, WdT, DM,  VDIM, (b-8704)%16,   (b-8704)/16,   t);
  else { for (int i = t; i < 5120; i += 256) zbase[i] = 0.f; }   // ps1,pq1,ps2,pq2,psd,pqd
}

// ============ 16-wave TLP GEMM: 1024 thr, 256xBN tile, double-buffered ============
// __launch_bounds__(1024,4): 1 block/CU -> 128 VGPR cap, no spill (round 9 verified).
// STATS (EPI 3/5): finalize output in acc-space, per-col sum/sumsq, shfl-reduce
// across kg, one atomicAdd per column per block.
// EPI: 0 f16+bias | 2 f16 *alpha*extra(f32) | 3 f32 (*alpha, +stats) | 4 f16 tanh(+bias) | 5 f32 (+bias+extra(f16), +stats)
template<int EPI, int BIG>
__global__ __launch_bounds__(1024, 4) void k_gemmT(const ushort* __restrict__ A, const ushort* __restrict__ Bt,
    int M, int N, int K, const float* __restrict__ bias, const void* __restrict__ extra,
    float alpha, float* __restrict__ Cf, ushort* __restrict__ Ch,
    float* __restrict__ psum, float* __restrict__ pqsum, int gxm1, int lg2gx)
{
  extern __shared__ ushort lds[];
  constexpr int BN   = BIG ? 256 : 128;
  constexpr int NI   = BIG ? 4 : 2;
  constexpr int WN   = NI * 16;
  constexpr int BSH  = BIG ? 16384 : 8192;
  constexpr int HALF = 16384 + BSH;
  constexpr int BJ   = BIG ? 2 : 1;
  const int tid = threadIdx.x, lane = tid & 63, w = tid >> 6;
  const int wm = (w >> 2) * 64, wn = (w & 3) * WN;
  int id = blockIdx.x;
  int nid = (id & 7) * ((int)gridDim.x >> 3) + (id >> 3);
  const int m0 = (nid >> lg2gx) * 256, n0 = (nid & gxm1) * BN;
  const int lr = lane & 15, kg = lane >> 4;
  f32x4 acc[4][NI] = {};
  const int nkt = K >> 6;
  const ushort* Ap = A + (long)m0 * K;
  const ushort* Bp = Bt + (long)n0 * K;
  int ra[2], ca[2];
  #pragma unroll
  for (int j = 0; j < 2; ++j){ int c = j*1024 + tid; ra[j] = c >> 3; ca[j] = (c & 7) ^ (ra[j] & 7); }
  auto stage = [&](int t, int buf){
    long ko = (long)t * 64;
    ushort* As = lds + buf*HALF;
    ushort* Bs = As + 16384;
    #pragma unroll
    for (int j = 0; j < 2; ++j)  gload16(Ap + (long)ra[j]*K + ko + ca[j]*8, As + (j*1024 + tid)*8);
    #pragma unroll
    for (int j = 0; j < BJ; ++j) gload16(Bp + (long)ra[j]*K + ko + ca[j]*8, Bs + (j*1024 + tid)*8);
  };
  stage(0, 0);
  __syncthreads();
  int cur = 0;
  for (int t = 0; t < nkt; ++t){
    if (t + 1 < nkt) stage(t + 1, cur ^ 1);   // issue first: full-tile latency lead
    const ushort* Ab = lds + cur*HALF;
    const ushort* Bb = Ab + 16384;
    f16x8 af[4], bf[NI];
    #pragma unroll
    for (int mi=0;mi<4;++mi){ int r = wm + mi*16 + lr; af[mi] = *(const f16x8*)&Ab[r*64 + ((kg ^ (r&7))*8)]; }
    #pragma unroll
    for (int ni=0;ni<NI;++ni){ int r = wn + ni*16 + lr; bf[ni] = *(const f16x8*)&Bb[r*64 + ((kg ^ (r&7))*8)]; }
    __builtin_amdgcn_s_setprio(1);
    #pragma unroll
    for (int mi=0;mi<4;++mi)
      #pragma unroll
      for (int ni=0;ni<NI;++ni)
        acc[mi][ni] = __builtin_amdgcn_mfma_f32_16x16x32_f16(af[mi], bf[ni], acc[mi][ni], 0,0,0);
    __builtin_amdgcn_s_setprio(0);
    #pragma unroll
    for (int mi=0;mi<4;++mi){ int r = wm + mi*16 + lr; af[mi] = *(const f16x8*)&Ab[r*64 + (((4+kg) ^ (r&7))*8)]; }
    #pragma unroll
    for (int ni=0;ni<NI;++ni){ int r = wn + ni*16 + lr; bf[ni] = *(const f16x8*)&Bb[r*64 + (((4+kg) ^ (r&7))*8)]; }
    __builtin_amdgcn_s_setprio(1);
    #pragma unroll
    for (int mi=0;mi<4;++mi)
      #pragma unroll
      for (int ni=0;ni<NI;++ni)
        acc[mi][ni] = __builtin_amdgcn_mfma_f32_16x16x32_f16(af[mi], bf[ni], acc[mi][ni], 0,0,0);
    __builtin_amdgcn_s_setprio(0);
    __syncthreads();                          // drains vm+lgkm: buf^1 staged, buf free
    cur ^= 1;
  }
  // ---- stats + acc-space finalize for EPI 3/5 ----
  if (EPI==3 || EPI==5){
    #pragma unroll
    for (int ni=0;ni<NI;++ni){
      int col = n0 + wn + ni*16 + lr;
      float bcol = (EPI==5) ? bias[col] : 0.f;
      float s = 0.f, q = 0.f;
      #pragma unroll
      for (int mi=0;mi<4;++mi){
        #pragma unroll
        for (int r=0;r<4;++r){
          float v = acc[mi][ni][r];
          if (EPI==3) v *= alpha;
          else {
            int row = m0 + wm + mi*16 + kg*4 + r;
            v += bcol + h2f(((const ushort*)extra)[(long)row*N + col]);
          }
          acc[mi][ni][r] = v;
          s += v; q += v*v;
        }
      }
      s += __shfl_xor(s,16); s += __shfl_xor(s,32);
      q += __shfl_xor(q,16); q += __shfl_xor(q,32);
      if (kg==0){ atomicAdd(&psum[col], s); atomicAdd(&pqsum[col], q); }
    }
  }
  // ---- epilogue: per-wave 64xWN transpose via LDS -> coalesced stores ----
  __syncthreads();
  float* Lw = ((float*)lds) + w * 16 * WN;
  #pragma unroll
  for (int mi = 0; mi < 4; ++mi){
    #pragma unroll
    for (int ni = 0; ni < NI; ++ni)
      #pragma unroll
      for (int r = 0; r < 4; ++r)
        Lw[(kg*4+r)*WN + ni*16 + lr] = acc[mi][ni][r];
    __syncthreads();
    #pragma unroll
    for (int tt = 0; tt < WN/16; ++tt){
      int fi = tt*64 + lane;
      int row16 = fi / (WN/4), c4 = fi % (WN/4);
      float4 v4 = *(float4*)&Lw[row16*WN + c4*4];
      int row = m0 + wm + mi*16 + row16;
      int col = n0 + wn + c4*4;
      if (EPI==0){
        float4 b4 = *(const float4*)&bias[col];
        ushort4 o; o.x=f2h(v4.x+b4.x); o.y=f2h(v4.y+b4.y); o.z=f2h(v4.z+b4.z); o.w=f2h(v4.w+b4.w);
        *(ushort4*)&Ch[(long)row*N + col] = o;
      } else if (EPI==2){
        float4 e4 = *(const float4*)((const float*)extra + (long)row*N + col);
        ushort4 o; o.x=f2h(v4.x*alpha*e4.x); o.y=f2h(v4.y*alpha*e4.y);
        o.z=f2h(v4.z*alpha*e4.z); o.w=f2h(v4.w*alpha*e4.w);
        *(ushort4*)&Ch[(long)row*N + col] = o;
      } else if (EPI==3 || EPI==5){
        *(float4*)&Cf[(long)row*N + col] = v4;   // finalized in acc-space
      } else if (EPI==4){
        float4 b4 = *(const float4*)&bias[col];
        ushort4 o; o.x=f2h(tanhf(v4.x+b4.x)); o.y=f2h(tanhf(v4.y+b4.y));
        o.z=f2h(tanhf(v4.z+b4.z)); o.w=f2h(tanhf(v4.w+b4.w));
        *(ushort4*)&Ch[(long)row*N + col] = o;
      }
    }
    __syncthreads();
  }
}

// ---------- legacy 128x128 GEMM (K, V^T, decoder) ----------
// EPI: 0 f16 out +bias | 1 f16 out transposed +bias | 6 f32 out +bias (+stats)
template<int EPI, bool A32>
__global__ __launch_bounds__(256) void k_gemm(const void* __restrict__ Av, const ushort* __restrict__ Bt,
    int M, int N, int K, const float* __restrict__ bias,
    float alpha, float* __restrict__ Cf, ushort* __restrict__ Ch,
    float* __restrict__ psum, float* __restrict__ pqsum, int gxm1, int lg2gx)
{
  __shared__ ushort As[128*64];
  __shared__ ushort Bs[128*64];
  const int tid = threadIdx.x, lane = tid & 63, w = tid>>6;
  const int wm = (w>>1)*64, wn = (w&1)*64;
  int id = blockIdx.x;
  int nid = (id & 7)*((int)gridDim.x >> 3) + (id >> 3);
  const int m0 = (nid >> lg2gx)*128, n0 = (nid & gxm1)*128;
  const int lr = lane & 15, kg = lane >> 4;
  f32x4 acc[4][4] = {};
  const int nkt = K >> 6;
  const ushort* Ah = (const ushort*)Av + (A32 ? 0 : (long)m0*K);
  const float*  Af = (const float*)Av  + (A32 ? (long)m0*K : 0);
  const ushort* Bp = Bt + (long)n0*K;
  int rowj[4], colj[4];
  #pragma unroll
  for (int j=0;j<4;++j){
    int c = w*256 + j*64 + lane;
    rowj[j] = c>>3; colj[j] = (c&7) ^ (rowj[j]&7);
  }
  float4 pa[4][2];
  if (A32){
    #pragma unroll
    for (int j=0;j<4;++j){
      const float* s = Af + (long)rowj[j]*K + colj[j]*8;
      pa[j][0] = *(const float4*)s; pa[j][1] = *(const float4*)(s+4);
    }
  }
  for (int kt=0; kt<nkt; ++kt){
    __syncthreads();
    long ko = (long)kt*64;
    if (A32){
      #pragma unroll
      for (int j=0;j<4;++j){
        uint4 o; o.x=pk2(pa[j][0].x,pa[j][0].y); o.y=pk2(pa[j][0].z,pa[j][0].w);
        o.z=pk2(pa[j][1].x,pa[j][1].y); o.w=pk2(pa[j][1].z,pa[j][1].w);
        *(uint4*)&As[(w*256 + j*64 + lane)*8] = o;
      }
    } else {
      #pragma unroll
      for (int j=0;j<4;++j)
        gload16(Ah + (long)rowj[j]*K + ko + colj[j]*8, As + (w*4+j)*512);
    }
    #pragma unroll
    for (int j=0;j<4;++j)
      gload16(Bp + (long)rowj[j]*K + ko + colj[j]*8, Bs + (w*4+j)*512);
    __syncthreads();
    if (A32 && kt+1 < nkt){
      long ko2 = ko + 64;
      #pragma unroll
      for (int j=0;j<4;++j){
        const float* s = Af + (long)rowj[j]*K + ko2 + colj[j]*8;
        pa[j][0] = *(const float4*)s; pa[j][1] = *(const float4*)(s+4);
      }
    }
    #pragma unroll
    for (int ks=0; ks<2; ++ks){
      f16x8 af[4], bfr[4];
      #pragma unroll
      for (int mi=0;mi<4;++mi){
        int r = wm + mi*16 + lr, c = ks*4 + kg;
        af[mi] = *(const f16x8*)&As[r*64 + ((c ^ (r&7))*8)];
      }
      #pragma unroll
      for (int ni=0;ni<4;++ni){
        int r = wn + ni*16 + lr, c = ks*4 + kg;
        bfr[ni] = *(const f16x8*)&Bs[r*64 + ((c ^ (r&7))*8)];
      }
      #pragma unroll
      for (int mi=0;mi<4;++mi)
        #pragma unroll
        for (int ni=0;ni<4;++ni)
          acc[mi][ni] = __builtin_amdgcn_mfma_f32_16x16x32_f16(af[mi], bfr[ni], acc[mi][ni], 0,0,0);
    }
  }
  if (EPI==6){   // bias + stats in acc-space
    #pragma unroll
    for (int ni=0;ni<4;++ni){
      int col = n0 + wn + ni*16 + lr;
      float bcol = bias[col];
      float s = 0.f, q = 0.f;
      #pragma unroll
      for (int mi=0;mi<4;++mi)
        #pragma unroll
        for (int r=0;r<4;++r){
          float v = acc[mi][ni][r] + bcol;
          acc[mi][ni][r] = v;
          s += v; q += v*v;
        }
      s += __shfl_xor(s,16); s += __shfl_xor(s,32);
      q += __shfl_xor(q,16); q += __shfl_xor(q,32);
      if (kg==0){ atomicAdd(&psum[col], s); atomicAdd(&pqsum[col], q); }
    }
  }
  __syncthreads();
  float* Lw = ((float*)As) + w*1024;
  #pragma unroll
  for (int mi=0;mi<4;++mi){
    #pragma unroll
    for (int ni=0;ni<4;++ni)
      #pragma unroll
      for (int r=0;r<4;++r)
        Lw[(kg*4+r)*64 + ni*16 + lr] = acc[mi][ni][r];
    __syncthreads();
    #pragma unroll
    for (int t=0;t<4;++t){
      int fi = t*64 + lane;
      int row16 = fi >> 4, c4 = fi & 15;
      float4 v4 = *(float4*)&Lw[row16*64 + c4*4];
      int row = m0 + wm + mi*16 + row16;
      int col = n0 + wn + c4*4;
      if (EPI==0){
        float4 b4 = *(const float4*)&bias[col];
        ushort4 o; o.x=f2h(v4.x+b4.x); o.y=f2h(v4.y+b4.y); o.z=f2h(v4.z+b4.z); o.w=f2h(v4.w+b4.w);
        *(ushort4*)&Ch[(long)row*N + col] = o;
      } else if (EPI==1){
        float4 b4 = *(const float4*)&bias[col];
        Ch[(long)(col+0)*M + row] = f2h(v4.x+b4.x);
        Ch[(long)(col+1)*M + row] = f2h(v4.y+b4.y);
        Ch[(long)(col+2)*M + row] = f2h(v4.z+b4.z);
        Ch[(long)(col+3)*M + row] = f2h(v4.w+b4.w);
      } else {
        *(float4*)&Cf[(long)row*N + col] = v4;   // EPI6: bias already applied
      }
    }
    __syncthreads();
  }
}

// ---------- row softmax over 4096 f16 cols, writes prob*512 as f16 ----------
__global__ __launch_bounds__(256) void k_softmax(const ushort* __restrict__ S, ushort* __restrict__ P){
  const long base = (long)blockIdx.x * 4096;
  const int t = threadIdx.x;
  uint u[8];
  *(uint4*)&u[0] = *(const uint4*)(S + base + t*16);
  *(uint4*)&u[4] = *(const uint4*)(S + base + t*16 + 8);
  float v[16];
  #pragma unroll
  for (int i=0;i<8;++i){ v[2*i]=h2f((ushort)(u[i]&0xffff)); v[2*i+1]=h2f((ushort)(u[i]>>16)); }
  float mx = -3.4e38f;
  #pragma unroll
  for (int i=0;i<16;++i) mx = fmaxf(mx, v[i]);
  #pragma unroll
  for (int off=1; off<64; off<<=1) mx = fmaxf(mx, __shfl_xor(mx, off));
  __shared__ float red[8];
  int wv = t>>6;
  if ((t&63)==0) red[wv]=mx;
  __syncthreads();
  mx = fmaxf(fmaxf(red[0],red[1]), fmaxf(red[2],red[3]));
  float e[16]; float sum=0.f;
  #pragma unroll
  for (int i=0;i<16;++i){ e[i]=__expf(v[i]-mx); sum+=e[i]; }
  #pragma unroll
  for (int off=1; off<64; off<<=1) sum += __shfl_xor(sum, off);
  if ((t&63)==0) red[4+wv]=sum;
  __syncthreads();
  sum = red[4]+red[5]+red[6]+red[7];
  float s = 512.f/sum;
  uint o[8];
  #pragma unroll
  for (int i=0;i<8;++i) o[i]=pk2(e[2*i]*s, e[2*i+1]*s);
  *(uint4*)(P + base + t*16)     = *(uint4*)&o[0];
  *(uint4*)(P + base + t*16 + 8) = *(uint4*)&o[4];
}

// ---------- batchnorm: finalize / apply ----------
__global__ __launch_bounds__(256) void k_bn_final(const float* __restrict__ ps, const float* __restrict__ pq,
    const float* __restrict__ gamma, const float* __restrict__ beta,
    float* __restrict__ scale, float* __restrict__ shift, int F, float invN, int nch){
  int c = blockIdx.x*256 + threadIdx.x;
  if (c>=F) return;
  float s=0.f,q=0.f;
  for (int i=0;i<nch;++i){ s+=ps[i*F+c]; q+=pq[i*F+c]; }
  float mu = s*invN, var = q*invN - mu*mu;
  float sc = gamma[c]*rsqrtf(var+1e-5f);
  scale[c]=sc; shift[c]=beta[c]-mu*sc;
}
__global__ __launch_bounds__(256) void k_bn_apply(const float* __restrict__ X, const float* __restrict__ scale, const float* __restrict__ shift,
    ushort* __restrict__ Xh, int F, long n){
  long i = ((long)blockIdx.x*256 + threadIdx.x)*4;
  if (i>=n) return;
  int c = (int)(i & (long)(F-1));
  float4 x = *(const float4*)(X+i);
  ushort4 o; o.x=f2h(x.x*scale[c]+shift[c]); o.y=f2h(x.y*scale[c+1]+shift[c+1]);
  o.z=f2h(x.z*scale[c+2]+shift[c+2]); o.w=f2h(x.w*scale[c+3]+shift[c+3]);
  *(ushort4*)(Xh+i)=o;
}
__global__ __launch_bounds__(256) void k_bn_tanh(const float* __restrict__ X, const float* __restrict__ scale, const float* __restrict__ shift,
    float* __restrict__ O, int F, long n){
  long i = ((long)blockIdx.x*256 + threadIdx.x)*4;
  if (i>=n) return;
  int c = (int)(i & (long)(F-1));
  float4 x = *(const float4*)(X+i);
  float4 y; y.x=tanhf(x.x*scale[c]+shift[c]); y.y=tanhf(x.y*scale[c+1]+shift[c+1]);
  y.z=tanhf(x.z*scale[c+2]+shift[c+2]); y.w=tanhf(x.w*scale[c+3]+shift[c+3]);
  *(float4*)(O+i)=y;
}

extern "C" void kernel_launch(void* const* d_in, const int* in_sizes, int n_in,
                              void* d_out, int out_size, void* d_ws, size_t ws_size,
                              hipStream_t stream){
  const float* src = (const float*)d_in[0];
  const float* a1  = (const float*)d_in[1];
  const float* a2  = (const float*)d_in[2];
  const float* lg  = (const float*)d_in[3];
  const float* Wq  = (const float*)d_in[4];
  const float* bq  = (const float*)d_in[5];
  const float* Wv  = (const float*)d_in[6];
  const float* bv  = (const float*)d_in[7];
  const float* W1  = (const float*)d_in[8];
  const float* b1  = (const float*)d_in[9];
  const float* W2  = (const float*)d_in[10];
  const float* b2  = (const float*)d_in[11];
  const float* g1  = (const float*)d_in[12];
  const float* be1 = (const float*)d_in[13];
  const float* g2  = (const float*)d_in[14];
  const float* be2 = (const float*)d_in[15];
  const float* Wd  = (const float*)d_in[16];
  const float* bd  = (const float*)d_in[17];
  const float* gd  = (const float*)d_in[18];
  const float* bed = (const float*)d_in[19];
  char* ws = (char*)d_ws;
  // region R0: src_h f16 [0,64M) -> scores f16 [0,64M) -> x_att f32 [0,32M)
  ushort* src_h = (ushort*)(ws + 0);
  ushort* scores= (ushort*)(ws + 0);
  float*  x_att = (float*) (ws + 0);
  // region R0b [64M,112M): a1_h f16 [64,96M) (conv_a1->K) ; later xnb [64,80M), hbuf [80,112M)
  ushort* a1_h  = (ushort*)(ws + 67108864);
  ushort* xnb   = (ushort*)(ws + 67108864);
  ushort* hbuf  = (ushort*)(ws + 83886080);
  // region R1: prob f16 [128,192M) -> x2 f32 [128,160), x2nb [160,176), y [176,192)
  ushort* prob  = (ushort*)(ws + 134217728);
  float*  x2    = (float*) (ws + 134217728);
  ushort* x2nb  = (ushort*)(ws + 167772160);
  float*  y     = (float*) (ws + 184549376);
  // persistent (>=192MiB)
  ushort* Qh    = (ushort*)(ws + 201326592);
  ushort* Kh    = (ushort*)(ws + 218103808);
  ushort* VTh   = (ushort*)(ws + 226492416);
  ushort* WqT   = (ushort*)(ws + 234881024);
  ushort* WvT   = (ushort*)(ws + 243269632);
  ushort* W1T   = (ushort*)(ws + 244318208);
  ushort* W2T   = (ushort*)(ws + 248512512);
  ushort* WdT   = (ushort*)(ws + 252706816);
  float*  sc1   = (float*) (ws + 254017536);
  float*  sh1   = (float*) (ws + 254021632);
  float*  sc2   = (float*) (ws + 254025728);
  float*  sh2   = (float*) (ws + 254029824);
  float*  scd   = (float*) (ws + 254033920);
  float*  shd   = (float*) (ws + 254035968);
  // BN stat buffers (contiguous, zeroed by k_prep)
  float*  ps1   = (float*) (ws + 254038016);
  float*  pq1   = (float*) (ws + 254042112);
  float*  ps2   = (float*) (ws + 254046208);
  float*  pq2   = (float*) (ws + 254050304);
  float*  psd   = (float*) (ws + 254054400);
  float*  pqd   = (float*) (ws + 254056448);

  (void)hipFuncSetAttribute((const void*)k_gemmT<0,0>, hipFuncAttributeMaxDynamicSharedMemorySize, 98304);
  (void)hipFuncSetAttribute((const void*)k_gemmT<2,1>, hipFuncAttributeMaxDynamicSharedMemorySize, 131072);
  (void)hipFuncSetAttribute((const void*)k_gemmT<3,0>, hipFuncAttributeMaxDynamicSharedMemorySize, 98304);
  (void)hipFuncSetAttribute((const void*)k_gemmT<4,1>, hipFuncAttributeMaxDynamicSharedMemorySize, 131072);
  (void)hipFuncSetAttribute((const void*)k_gemmT<5,0>, hipFuncAttributeMaxDynamicSharedMemorySize, 98304);

  dim3 b256(256), b1024(1024);
  // pre-Q timeline identical to round 12: conv(src) then prep then Q
  k_conv<<<dim3(16384), b256, 0, stream>>>(src, src_h, (long)NSRC*QDIM);
  k_prep<<<dim3(9217), b256, 0, stream>>>(Wq, Wv, W1, W2, Wd, WqT, WvT, W1T, W2T, WdT, ps1);
  k_gemmT<0,0><<<dim3(256), b1024, 98304, stream>>>(src_h, WqT, NSRC, DM, QDIM, bq, nullptr, 1.f, nullptr, Qh, nullptr, nullptr, 7, 3);
  // a1 conversion AFTER Q, then K on proven f16 gload path; V^T legacy A32
  k_conv<<<dim3(8192), b256, 0, stream>>>(a1, a1_h, (long)MANC*QDIM);
  k_gemm<0,false><<<dim3(256), b256, 0, stream>>>(a1_h, WqT, MANC, DM, QDIM, bq, 1.f, nullptr, Kh, nullptr, nullptr, 7, 3);
  k_gemm<1,true><<<dim3(256), b256, 0, stream>>>(a2, WvT, MANC, DM, VDIM, bv, 1.f, nullptr, VTh, nullptr, nullptr, 7, 3);
  // scores(f16) = (Q K^T)/32 * label_graph ; softmax(f16) ; x = prob V (+BN1 stats)
  k_gemmT<2,1><<<dim3(512), b1024, 131072, stream>>>(Qh, Kh, NSRC, MANC, DM, nullptr, lg, 0.03125f, nullptr, scores, nullptr, nullptr, 15, 4);
  k_softmax<<<dim3(NSRC), b256, 0, stream>>>(scores, prob);
  k_gemmT<3,0><<<dim3(256), b1024, 98304, stream>>>(prob, VTh, NSRC, DM, MANC, nullptr, nullptr, 1.f/512.f, x_att, nullptr, ps1, pq1, 7, 3);
  // BN1
  k_bn_final<<<dim3(DM/256), b256, 0, stream>>>(ps1, pq1, g1, be1, sc1, sh1, DM, 1.f/NSRC, 1);
  k_bn_apply<<<dim3(8192), b256, 0, stream>>>(x_att, sc1, sh1, xnb, DM, (long)NSRC*DM);
  // FFN (FFN2 fuses residual + BN2 stats)
  k_gemmT<4,1><<<dim3(256), b1024, 131072, stream>>>(xnb, W1T, NSRC, FFD, DM, b1, nullptr, 1.f, nullptr, hbuf, nullptr, nullptr, 7, 3);
  k_gemmT<5,0><<<dim3(256), b1024, 98304, stream>>>(hbuf, W2T, NSRC, DM, FFD, b2, xnb, 1.f, x2, nullptr, ps2, pq2, 7, 3);
  // BN2
  k_bn_final<<<dim3(DM/256), b256, 0, stream>>>(ps2, pq2, g2, be2, sc2, sh2, DM, 1.f/NSRC, 1);
  k_bn_apply<<<dim3(8192), b256, 0, stream>>>(x2, sc2, sh2, x2nb, DM, (long)NSRC*DM);
  // decoder (+BNd stats) + BN + tanh
  k_gemm<6,false><<<dim3(256), b256, 0, stream>>>(x2nb, WdT, NSRC, VDIM, DM, bd, 1.f, y, nullptr, psd, pqd, 3, 2);
  k_bn_final<<<dim3(2), b256, 0, stream>>>(psd, pqd, gd, bed, scd, shd, VDIM, 1.f/NSRC, 1);
  k_bn_tanh<<<dim3(4096), b256, 0, stream>>>(y, scd, shd, (float*)d_out, VDIM, (long)NSRC*VDIM);
}

// Round 16
// 568.009 us; speedup vs baseline: 1.0556x; 1.0331x over previous
//
#include <hip/hip_runtime.h>

typedef __attribute__((ext_vector_type(4))) float f32x4;
typedef __attribute__((ext_vector_type(8))) _Float16 f16x8;

#define NSRC 8192
#define MANC 4096
#define QDIM 4096
#define VDIM 512
#define DM   1024
#define FFD  2048

__device__ __forceinline__ ushort f2h(float f){ _Float16 h=(_Float16)f; return __builtin_bit_cast(ushort,h); }
__device__ __forceinline__ float h2f(ushort u){ _Float16 h=__builtin_bit_cast(_Float16,u); return (float)h; }
__device__ __forceinline__ uint pk2(float a,float b){ return (uint)f2h(a) | ((uint)f2h(b)<<16); }

__device__ __forceinline__ void gload16(const ushort* g, ushort* l){
  __builtin_amdgcn_global_load_lds(
    (const __attribute__((address_space(1))) unsigned int*)g,
    (__attribute__((address_space(3))) unsigned int*)l, 16, 0, 0);
}

// ---------- f32 -> f16 convert (src only) ----------
__global__ __launch_bounds__(256) void k_conv(const float* __restrict__ in, ushort* __restrict__ out, long n){
  long i = ((long)blockIdx.x*256 + threadIdx.x)*8;
  if (i >= n) return;
  float4 a = *(const float4*)(in+i);
  float4 b = *(const float4*)(in+i+4);
  uint4 o; o.x=pk2(a.x,a.y); o.y=pk2(a.z,a.w); o.z=pk2(b.x,b.y); o.w=pk2(b.z,b.w);
  *(uint4*)(out+i) = o;
}

// ---------- merged weight transposes + stat-buffer zeroing ----------
__device__ __forceinline__ void tr32(const float* __restrict__ W, ushort* __restrict__ WT,
                                     int K, int N, int bx, int by, int tid){
  __shared__ float tile[32][33];
  int n0 = bx*32, k0 = by*32;
  int tx = tid & 31, ty = tid >> 5;
  #pragma unroll
  for (int i=0;i<4;++i) tile[ty+i*8][tx] = W[(long)(k0+ty+i*8)*N + n0+tx];
  __syncthreads();
  #pragma unroll
  for (int i=0;i<4;++i){ int nn=ty+i*8; WT[(long)(n0+nn)*K + k0+tx] = f2h(tile[tx][nn]); }
}
__global__ __launch_bounds__(256) void k_prep(const float* __restrict__ Wq, const float* __restrict__ Wv,
    const float* __restrict__ W1, const float* __restrict__ W2, const float* __restrict__ Wd,
    ushort* __restrict__ WqT, ushort* __restrict__ WvT, ushort* __restrict__ W1T,
    ushort* __restrict__ W2T, ushort* __restrict__ WdT, float* __restrict__ zbase){
  int b = blockIdx.x, t = threadIdx.x;
  if (b < 4096)                 tr32(Wq, WqT, QDIM, DM,  b % 32,        b / 32,        t);
  else if (b < 4608)            tr32(Wv, WvT, VDIM, DM,  (b-4096)%32,   (b-4096)/32,   t);
  else if (b < 6656)            tr32(W1, W1T, DM,  FFD,  (b-4608)%64,   (b-4608)/64,   t);
  else if (b < 8704)            tr32(W2, W2T, FFD, DM,   (b-6656)%32,   (b-6656)/32,   t);
  else if (b < 9216)            tr32(Wd, WdT, DM,  VDIM, (b-8704)%16,   (b-8704)/16,   t);
  else { for (int i = t; i < 5120; i += 256) zbase[i] = 0.f; }   // ps1,pq1,ps2,pq2,psd,pqd
}

// ============ 16-wave TLP GEMM: 1024 thr, 256xBN tile, double-buffered ============
// __launch_bounds__(1024,4): 1 block/CU -> 128 VGPR cap, no spill (round 9 verified).
// STATS (EPI 3/5): finalize output in acc-space, per-col sum/sumsq, shfl-reduce
// across kg, one atomicAdd per column per block.
// EPI: 0 f16+bias | 2 f16 *alpha*extra(f32) | 3 f32 (*alpha, +stats) | 4 f16 tanh(+bias) | 5 f32 (+bias+extra(f16), +stats)
template<int EPI, int BIG>
__global__ __launch_bounds__(1024, 4) void k_gemmT(const ushort* __restrict__ A, const ushort* __restrict__ Bt,
    int M, int N, int K, const float* __restrict__ bias, const void* __restrict__ extra,
    float alpha, float* __restrict__ Cf, ushort* __restrict__ Ch,
    float* __restrict__ psum, float* __restrict__ pqsum, int gxm1, int lg2gx)
{
  extern __shared__ ushort lds[];
  constexpr int BN   = BIG ? 256 : 128;
  constexpr int NI   = BIG ? 4 : 2;
  constexpr int WN   = NI * 16;
  constexpr int BSH  = BIG ? 16384 : 8192;
  constexpr int HALF = 16384 + BSH;
  constexpr int BJ   = BIG ? 2 : 1;
  const int tid = threadIdx.x, lane = tid & 63, w = tid >> 6;
  const int wm = (w >> 2) * 64, wn = (w & 3) * WN;
  int id = blockIdx.x;
  int nid = (id & 7) * ((int)gridDim.x >> 3) + (id >> 3);
  const int m0 = (nid >> lg2gx) * 256, n0 = (nid & gxm1) * BN;
  const int lr = lane & 15, kg = lane >> 4;
  f32x4 acc[4][NI] = {};
  const int nkt = K >> 6;
  const ushort* Ap = A + (long)m0 * K;
  const ushort* Bp = Bt + (long)n0 * K;
  int ra[2], ca[2];
  #pragma unroll
  for (int j = 0; j < 2; ++j){ int c = j*1024 + tid; ra[j] = c >> 3; ca[j] = (c & 7) ^ (ra[j] & 7); }
  auto stage = [&](int t, int buf){
    long ko = (long)t * 64;
    ushort* As = lds + buf*HALF;
    ushort* Bs = As + 16384;
    #pragma unroll
    for (int j = 0; j < 2; ++j)  gload16(Ap + (long)ra[j]*K + ko + ca[j]*8, As + (j*1024 + tid)*8);
    #pragma unroll
    for (int j = 0; j < BJ; ++j) gload16(Bp + (long)ra[j]*K + ko + ca[j]*8, Bs + (j*1024 + tid)*8);
  };
  stage(0, 0);
  __syncthreads();
  int cur = 0;
  for (int t = 0; t < nkt; ++t){
    if (t + 1 < nkt) stage(t + 1, cur ^ 1);   // issue first: full-tile latency lead
    const ushort* Ab = lds + cur*HALF;
    const ushort* Bb = Ab + 16384;
    f16x8 af[4], bf[NI];
    #pragma unroll
    for (int mi=0;mi<4;++mi){ int r = wm + mi*16 + lr; af[mi] = *(const f16x8*)&Ab[r*64 + ((kg ^ (r&7))*8)]; }
    #pragma unroll
    for (int ni=0;ni<NI;++ni){ int r = wn + ni*16 + lr; bf[ni] = *(const f16x8*)&Bb[r*64 + ((kg ^ (r&7))*8)]; }
    __builtin_amdgcn_s_setprio(1);
    #pragma unroll
    for (int mi=0;mi<4;++mi)
      #pragma unroll
      for (int ni=0;ni<NI;++ni)
        acc[mi][ni] = __builtin_amdgcn_mfma_f32_16x16x32_f16(af[mi], bf[ni], acc[mi][ni], 0,0,0);
    __builtin_amdgcn_s_setprio(0);
    #pragma unroll
    for (int mi=0;mi<4;++mi){ int r = wm + mi*16 + lr; af[mi] = *(const f16x8*)&Ab[r*64 + (((4+kg) ^ (r&7))*8)]; }
    #pragma unroll
    for (int ni=0;ni<NI;++ni){ int r = wn + ni*16 + lr; bf[ni] = *(const f16x8*)&Bb[r*64 + (((4+kg) ^ (r&7))*8)]; }
    __builtin_amdgcn_s_setprio(1);
    #pragma unroll
    for (int mi=0;mi<4;++mi)
      #pragma unroll
      for (int ni=0;ni<NI;++ni)
        acc[mi][ni] = __builtin_amdgcn_mfma_f32_16x16x32_f16(af[mi], bf[ni], acc[mi][ni], 0,0,0);
    __builtin_amdgcn_s_setprio(0);
    __syncthreads();                          // drains vm+lgkm: buf^1 staged, buf free
    cur ^= 1;
  }
  // ---- stats + acc-space finalize for EPI 3/5 ----
  if (EPI==3 || EPI==5){
    #pragma unroll
    for (int ni=0;ni<NI;++ni){
      int col = n0 + wn + ni*16 + lr;
      float bcol = (EPI==5) ? bias[col] : 0.f;
      float s = 0.f, q = 0.f;
      #pragma unroll
      for (int mi=0;mi<4;++mi){
        #pragma unroll
        for (int r=0;r<4;++r){
          float v = acc[mi][ni][r];
          if (EPI==3) v *= alpha;
          else {
            int row = m0 + wm + mi*16 + kg*4 + r;
            v += bcol + h2f(((const ushort*)extra)[(long)row*N + col]);
          }
          acc[mi][ni][r] = v;
          s += v; q += v*v;
        }
      }
      s += __shfl_xor(s,16); s += __shfl_xor(s,32);
      q += __shfl_xor(q,16); q += __shfl_xor(q,32);
      if (kg==0){ atomicAdd(&psum[col], s); atomicAdd(&pqsum[col], q); }
    }
  }
  // ---- epilogue: per-wave 64xWN transpose via LDS -> coalesced stores ----
  __syncthreads();
  float* Lw = ((float*)lds) + w * 16 * WN;
  #pragma unroll
  for (int mi = 0; mi < 4; ++mi){
    #pragma unroll
    for (int ni = 0; ni < NI; ++ni)
      #pragma unroll
      for (int r = 0; r < 4; ++r)
        Lw[(kg*4+r)*WN + ni*16 + lr] = acc[mi][ni][r];
    __syncthreads();
    #pragma unroll
    for (int tt = 0; tt < WN/16; ++tt){
      int fi = tt*64 + lane;
      int row16 = fi / (WN/4), c4 = fi % (WN/4);
      float4 v4 = *(float4*)&Lw[row16*WN + c4*4];
      int row = m0 + wm + mi*16 + row16;
      int col = n0 + wn + c4*4;
      if (EPI==0){
        float4 b4 = *(const float4*)&bias[col];
        ushort4 o; o.x=f2h(v4.x+b4.x); o.y=f2h(v4.y+b4.y); o.z=f2h(v4.z+b4.z); o.w=f2h(v4.w+b4.w);
        *(ushort4*)&Ch[(long)row*N + col] = o;
      } else if (EPI==2){
        float4 e4 = *(const float4*)((const float*)extra + (long)row*N + col);
        ushort4 o; o.x=f2h(v4.x*alpha*e4.x); o.y=f2h(v4.y*alpha*e4.y);
        o.z=f2h(v4.z*alpha*e4.z); o.w=f2h(v4.w*alpha*e4.w);
        *(ushort4*)&Ch[(long)row*N + col] = o;
      } else if (EPI==3 || EPI==5){
        *(float4*)&Cf[(long)row*N + col] = v4;   // finalized in acc-space
      } else if (EPI==4){
        float4 b4 = *(const float4*)&bias[col];
        ushort4 o; o.x=f2h(tanhf(v4.x+b4.x)); o.y=f2h(tanhf(v4.y+b4.y));
        o.z=f2h(tanhf(v4.z+b4.z)); o.w=f2h(tanhf(v4.w+b4.w));
        *(ushort4*)&Ch[(long)row*N + col] = o;
      }
    }
    __syncthreads();
  }
}

// ---------- legacy 128x128 GEMM (K, V^T, decoder) ----------
// EPI: 0 f16 out +bias | 1 f16 out transposed +bias | 6 f32 out +bias (+stats)
template<int EPI, bool A32>
__global__ __launch_bounds__(256) void k_gemm(const void* __restrict__ Av, const ushort* __restrict__ Bt,
    int M, int N, int K, const float* __restrict__ bias,
    float alpha, float* __restrict__ Cf, ushort* __restrict__ Ch,
    float* __restrict__ psum, float* __restrict__ pqsum, int gxm1, int lg2gx)
{
  __shared__ ushort As[128*64];
  __shared__ ushort Bs[128*64];
  const int tid = threadIdx.x, lane = tid & 63, w = tid>>6;
  const int wm = (w>>1)*64, wn = (w&1)*64;
  int id = blockIdx.x;
  int nid = (id & 7)*((int)gridDim.x >> 3) + (id >> 3);
  const int m0 = (nid >> lg2gx)*128, n0 = (nid & gxm1)*128;
  const int lr = lane & 15, kg = lane >> 4;
  f32x4 acc[4][4] = {};
  const int nkt = K >> 6;
  const ushort* Ah = (const ushort*)Av + (A32 ? 0 : (long)m0*K);
  const float*  Af = (const float*)Av  + (A32 ? (long)m0*K : 0);
  const ushort* Bp = Bt + (long)n0*K;
  int rowj[4], colj[4];
  #pragma unroll
  for (int j=0;j<4;++j){
    int c = w*256 + j*64 + lane;
    rowj[j] = c>>3; colj[j] = (c&7) ^ (rowj[j]&7);
  }
  float4 pa[4][2];
  if (A32){
    #pragma unroll
    for (int j=0;j<4;++j){
      const float* s = Af + (long)rowj[j]*K + colj[j]*8;
      pa[j][0] = *(const float4*)s; pa[j][1] = *(const float4*)(s+4);
    }
  }
  for (int kt=0; kt<nkt; ++kt){
    __syncthreads();
    long ko = (long)kt*64;
    if (A32){
      #pragma unroll
      for (int j=0;j<4;++j){
        uint4 o; o.x=pk2(pa[j][0].x,pa[j][0].y); o.y=pk2(pa[j][0].z,pa[j][0].w);
        o.z=pk2(pa[j][1].x,pa[j][1].y); o.w=pk2(pa[j][1].z,pa[j][1].w);
        *(uint4*)&As[(w*256 + j*64 + lane)*8] = o;
      }
    } else {
      #pragma unroll
      for (int j=0;j<4;++j)
        gload16(Ah + (long)rowj[j]*K + ko + colj[j]*8, As + (w*4+j)*512);
    }
    #pragma unroll
    for (int j=0;j<4;++j)
      gload16(Bp + (long)rowj[j]*K + ko + colj[j]*8, Bs + (w*4+j)*512);
    __syncthreads();
    if (A32 && kt+1 < nkt){
      long ko2 = ko + 64;
      #pragma unroll
      for (int j=0;j<4;++j){
        const float* s = Af + (long)rowj[j]*K + ko2 + colj[j]*8;
        pa[j][0] = *(const float4*)s; pa[j][1] = *(const float4*)(s+4);
      }
    }
    #pragma unroll
    for (int ks=0; ks<2; ++ks){
      f16x8 af[4], bfr[4];
      #pragma unroll
      for (int mi=0;mi<4;++mi){
        int r = wm + mi*16 + lr, c = ks*4 + kg;
        af[mi] = *(const f16x8*)&As[r*64 + ((c ^ (r&7))*8)];
      }
      #pragma unroll
      for (int ni=0;ni<4;++ni){
        int r = wn + ni*16 + lr, c = ks*4 + kg;
        bfr[ni] = *(const f16x8*)&Bs[r*64 + ((c ^ (r&7))*8)];
      }
      #pragma unroll
      for (int mi=0;mi<4;++mi)
        #pragma unroll
        for (int ni=0;ni<4;++ni)
          acc[mi][ni] = __builtin_amdgcn_mfma_f32_16x16x32_f16(af[mi], bfr[ni], acc[mi][ni], 0,0,0);
    }
  }
  if (EPI==6){   // bias + stats in acc-space
    #pragma unroll
    for (int ni=0;ni<4;++ni){
      int col = n0 + wn + ni*16 + lr;
      float bcol = bias[col];
      float s = 0.f, q = 0.f;
      #pragma unroll
      for (int mi=0;mi<4;++mi)
        #pragma unroll
        for (int r=0;r<4;++r){
          float v = acc[mi][ni][r] + bcol;
          acc[mi][ni][r] = v;
          s += v; q += v*v;
        }
      s += __shfl_xor(s,16); s += __shfl_xor(s,32);
      q += __shfl_xor(q,16); q += __shfl_xor(q,32);
      if (kg==0){ atomicAdd(&psum[col], s); atomicAdd(&pqsum[col], q); }
    }
  }
  __syncthreads();
  float* Lw = ((float*)As) + w*1024;
  #pragma unroll
  for (int mi=0;mi<4;++mi){
    #pragma unroll
    for (int ni=0;ni<4;++ni)
      #pragma unroll
      for (int r=0;r<4;++r)
        Lw[(kg*4+r)*64 + ni*16 + lr] = acc[mi][ni][r];
    __syncthreads();
    #pragma unroll
    for (int t=0;t<4;++t){
      int fi = t*64 + lane;
      int row16 = fi >> 4, c4 = fi & 15;
      float4 v4 = *(float4*)&Lw[row16*64 + c4*4];
      int row = m0 + wm + mi*16 + row16;
      int col = n0 + wn + c4*4;
      if (EPI==0){
        float4 b4 = *(const float4*)&bias[col];
        ushort4 o; o.x=f2h(v4.x+b4.x); o.y=f2h(v4.y+b4.y); o.z=f2h(v4.z+b4.z); o.w=f2h(v4.w+b4.w);
        *(ushort4*)&Ch[(long)row*N + col] = o;
      } else if (EPI==1){
        float4 b4 = *(const float4*)&bias[col];
        Ch[(long)(col+0)*M + row] = f2h(v4.x+b4.x);
        Ch[(long)(col+1)*M + row] = f2h(v4.y+b4.y);
        Ch[(long)(col+2)*M + row] = f2h(v4.z+b4.z);
        Ch[(long)(col+3)*M + row] = f2h(v4.w+b4.w);
      } else {
        *(float4*)&Cf[(long)row*N + col] = v4;   // EPI6: bias already applied
      }
    }
    __syncthreads();
  }
}

// ---------- row softmax over 4096 f16 cols, writes prob*512 as f16 ----------
__global__ __launch_bounds__(256) void k_softmax(const ushort* __restrict__ S, ushort* __restrict__ P){
  const long base = (long)blockIdx.x * 4096;
  const int t = threadIdx.x;
  uint u[8];
  *(uint4*)&u[0] = *(const uint4*)(S + base + t*16);
  *(uint4*)&u[4] = *(const uint4*)(S + base + t*16 + 8);
  float v[16];
  #pragma unroll
  for (int i=0;i<8;++i){ v[2*i]=h2f((ushort)(u[i]&0xffff)); v[2*i+1]=h2f((ushort)(u[i]>>16)); }
  float mx = -3.4e38f;
  #pragma unroll
  for (int i=0;i<16;++i) mx = fmaxf(mx, v[i]);
  #pragma unroll
  for (int off=1; off<64; off<<=1) mx = fmaxf(mx, __shfl_xor(mx, off));
  __shared__ float red[8];
  int wv = t>>6;
  if ((t&63)==0) red[wv]=mx;
  __syncthreads();
  mx = fmaxf(fmaxf(red[0],red[1]), fmaxf(red[2],red[3]));
  float e[16]; float sum=0.f;
  #pragma unroll
  for (int i=0;i<16;++i){ e[i]=__expf(v[i]-mx); sum+=e[i]; }
  #pragma unroll
  for (int off=1; off<64; off<<=1) sum += __shfl_xor(sum, off);
  if ((t&63)==0) red[4+wv]=sum;
  __syncthreads();
  sum = red[4]+red[5]+red[6]+red[7];
  float s = 512.f/sum;
  uint o[8];
  #pragma unroll
  for (int i=0;i<8;++i) o[i]=pk2(e[2*i]*s, e[2*i+1]*s);
  *(uint4*)(P + base + t*16)     = *(uint4*)&o[0];
  *(uint4*)(P + base + t*16 + 8) = *(uint4*)&o[4];
}

// ---------- batchnorm: finalize / apply ----------
__global__ __launch_bounds__(256) void k_bn_final(const float* __restrict__ ps, const float* __restrict__ pq,
    const float* __restrict__ gamma, const float* __restrict__ beta,
    float* __restrict__ scale, float* __restrict__ shift, int F, float invN, int nch){
  int c = blockIdx.x*256 + threadIdx.x;
  if (c>=F) return;
  float s=0.f,q=0.f;
  for (int i=0;i<nch;++i){ s+=ps[i*F+c]; q+=pq[i*F+c]; }
  float mu = s*invN, var = q*invN - mu*mu;
  float sc = gamma[c]*rsqrtf(var+1e-5f);
  scale[c]=sc; shift[c]=beta[c]-mu*sc;
}
__global__ __launch_bounds__(256) void k_bn_apply(const float* __restrict__ X, const float* __restrict__ scale, const float* __restrict__ shift,
    ushort* __restrict__ Xh, int F, long n){
  long i = ((long)blockIdx.x*256 + threadIdx.x)*4;
  if (i>=n) return;
  int c = (int)(i & (long)(F-1));
  float4 x = *(const float4*)(X+i);
  ushort4 o; o.x=f2h(x.x*scale[c]+shift[c]); o.y=f2h(x.y*scale[c+1]+shift[c+1]);
  o.z=f2h(x.z*scale[c+2]+shift[c+2]); o.w=f2h(x.w*scale[c+3]+shift[c+3]);
  *(ushort4*)(Xh+i)=o;
}
__global__ __launch_bounds__(256) void k_bn_tanh(const float* __restrict__ X, const float* __restrict__ scale, const float* __restrict__ shift,
    float* __restrict__ O, int F, long n){
  long i = ((long)blockIdx.x*256 + threadIdx.x)*4;
  if (i>=n) return;
  int c = (int)(i & (long)(F-1));
  float4 x = *(const float4*)(X+i);
  float4 y; y.x=tanhf(x.x*scale[c]+shift[c]); y.y=tanhf(x.y*scale[c+1]+shift[c+1]);
  y.z=tanhf(x.z*scale[c+2]+shift[c+2]); y.w=tanhf(x.w*scale[c+3]+shift[c+3]);
  *(float4*)(O+i)=y;
}

extern "C" void kernel_launch(void* const* d_in, const int* in_sizes, int n_in,
                              void* d_out, int out_size, void* d_ws, size_t ws_size,
                              hipStream_t stream){
  const float* src = (const float*)d_in[0];
  const float* a1  = (const float*)d_in[1];
  const float* a2  = (const float*)d_in[2];
  const float* lg  = (const float*)d_in[3];
  const float* Wq  = (const float*)d_in[4];
  const float* bq  = (const float*)d_in[5];
  const float* Wv  = (const float*)d_in[6];
  const float* bv  = (const float*)d_in[7];
  const float* W1  = (const float*)d_in[8];
  const float* b1  = (const float*)d_in[9];
  const float* W2  = (const float*)d_in[10];
  const float* b2  = (const float*)d_in[11];
  const float* g1  = (const float*)d_in[12];
  const float* be1 = (const float*)d_in[13];
  const float* g2  = (const float*)d_in[14];
  const float* be2 = (const float*)d_in[15];
  const float* Wd  = (const float*)d_in[16];
  const float* bd  = (const float*)d_in[17];
  const float* gd  = (const float*)d_in[18];
  const float* bed = (const float*)d_in[19];
  char* ws = (char*)d_ws;
  // region R0: src_h f16 [0,64M) -> scores f16 [0,64M) -> x_att f32 [0,32M)
  ushort* src_h = (ushort*)(ws + 0);
  ushort* scores= (ushort*)(ws + 0);
  float*  x_att = (float*) (ws + 0);
  ushort* xnb   = (ushort*)(ws + 67108864);
  ushort* hbuf  = (ushort*)(ws + 83886080);
  // region R1: prob f16 [128,192M) -> x2 f32 [128,160), x2nb [160,176), y [176,192)
  ushort* prob  = (ushort*)(ws + 134217728);
  float*  x2    = (float*) (ws + 134217728);
  ushort* x2nb  = (ushort*)(ws + 167772160);
  float*  y     = (float*) (ws + 184549376);
  // persistent (>=192MiB)
  ushort* Qh    = (ushort*)(ws + 201326592);
  ushort* Kh    = (ushort*)(ws + 218103808);
  ushort* VTh   = (ushort*)(ws + 226492416);
  ushort* WqT   = (ushort*)(ws + 234881024);
  ushort* WvT   = (ushort*)(ws + 243269632);
  ushort* W1T   = (ushort*)(ws + 244318208);
  ushort* W2T   = (ushort*)(ws + 248512512);
  ushort* WdT   = (ushort*)(ws + 252706816);
  float*  sc1   = (float*) (ws + 254017536);
  float*  sh1   = (float*) (ws + 254021632);
  float*  sc2   = (float*) (ws + 254025728);
  float*  sh2   = (float*) (ws + 254029824);
  float*  scd   = (float*) (ws + 254033920);
  float*  shd   = (float*) (ws + 254035968);
  // BN stat buffers (contiguous, zeroed by k_prep)
  float*  ps1   = (float*) (ws + 254038016);
  float*  pq1   = (float*) (ws + 254042112);
  float*  ps2   = (float*) (ws + 254046208);
  float*  pq2   = (float*) (ws + 254050304);
  float*  psd   = (float*) (ws + 254054400);
  float*  pqd   = (float*) (ws + 254056448);

  (void)hipFuncSetAttribute((const void*)k_gemmT<0,0>, hipFuncAttributeMaxDynamicSharedMemorySize, 98304);
  (void)hipFuncSetAttribute((const void*)k_gemmT<2,1>, hipFuncAttributeMaxDynamicSharedMemorySize, 131072);
  (void)hipFuncSetAttribute((const void*)k_gemmT<3,0>, hipFuncAttributeMaxDynamicSharedMemorySize, 98304);
  (void)hipFuncSetAttribute((const void*)k_gemmT<4,1>, hipFuncAttributeMaxDynamicSharedMemorySize, 131072);
  (void)hipFuncSetAttribute((const void*)k_gemmT<5,0>, hipFuncAttributeMaxDynamicSharedMemorySize, 98304);

  dim3 b256(256), b1024(1024);
  k_conv<<<dim3(16384), b256, 0, stream>>>(src, src_h, (long)NSRC*QDIM);
  k_prep<<<dim3(9217), b256, 0, stream>>>(Wq, Wv, W1, W2, Wd, WqT, WvT, W1T, W2T, WdT, ps1);
  // Q (gload_lds path), K and V^T (legacy, fused f32 A)
  k_gemmT<0,0><<<dim3(256), b1024, 98304, stream>>>(src_h, WqT, NSRC, DM, QDIM, bq, nullptr, 1.f, nullptr, Qh, nullptr, nullptr, 7, 3);
  k_gemm<0,true><<<dim3(256), b256, 0, stream>>>(a1, WqT, MANC, DM, QDIM, bq, 1.f, nullptr, Kh, nullptr, nullptr, 7, 3);
  k_gemm<1,true><<<dim3(256), b256, 0, stream>>>(a2, WvT, MANC, DM, VDIM, bv, 1.f, nullptr, VTh, nullptr, nullptr, 7, 3);
  // scores(f16) = (Q K^T)/32 * label_graph ; softmax(f16) ; x = prob V (+BN1 stats)
  k_gemmT<2,1><<<dim3(512), b1024, 131072, stream>>>(Qh, Kh, NSRC, MANC, DM, nullptr, lg, 0.03125f, nullptr, scores, nullptr, nullptr, 15, 4);
  k_softmax<<<dim3(NSRC), b256, 0, stream>>>(scores, prob);
  k_gemmT<3,0><<<dim3(256), b1024, 98304, stream>>>(prob, VTh, NSRC, DM, MANC, nullptr, nullptr, 1.f/512.f, x_att, nullptr, ps1, pq1, 7, 3);
  // BN1
  k_bn_final<<<dim3(DM/256), b256, 0, stream>>>(ps1, pq1, g1, be1, sc1, sh1, DM, 1.f/NSRC, 1);
  k_bn_apply<<<dim3(8192), b256, 0, stream>>>(x_att, sc1, sh1, xnb, DM, (long)NSRC*DM);
  // FFN (FFN2 fuses residual + BN2 stats)
  k_gemmT<4,1><<<dim3(256), b1024, 131072, stream>>>(xnb, W1T, NSRC, FFD, DM, b1, nullptr, 1.f, nullptr, hbuf, nullptr, nullptr, 7, 3);
  k_gemmT<5,0><<<dim3(256), b1024, 98304, stream>>>(hbuf, W2T, NSRC, DM, FFD, b2, xnb, 1.f, x2, nullptr, ps2, pq2, 7, 3);
  // BN2
  k_bn_final<<<dim3(DM/256), b256, 0, stream>>>(ps2, pq2, g2, be2, sc2, sh2, DM, 1.f/NSRC, 1);
  k_bn_apply<<<dim3(8192), b256, 0, stream>>>(x2, sc2, sh2, x2nb, DM, (long)NSRC*DM);
  // decoder (+BNd stats) + BN + tanh
  k_gemm<6,false><<<dim3(256), b256, 0, stream>>>(x2nb, WdT, NSRC, VDIM, DM, bd, 1.f, y, nullptr, psd, pqd, 3, 2);
  k_bn_final<<<dim3(2), b256, 0, stream>>>(psd, pqd, gd, bed, scd, shd, VDIM, 1.f/NSRC, 1);
  k_bn_tanh<<<dim3(4096), b256, 0, stream>>>(y, scd, shd, (float*)d_out, VDIM, (long)NSRC*VDIM);
}